// Round 1
// baseline (1183.076 us; speedup 1.0000x reference)
//
#include <hip/hip_runtime.h>

// Problem: bidirectional masked LSTM (Keras semantics), only last timestep consumed.
//   B=256, T=2048, VOCAB=6, EMB=64, HID=64.
// Key reductions:
//   - bwd direction at t=T-1 == ONE lstm step from zero state (U_b unused).
//   - x@W+b has only 6 values per direction -> precompute zx[6][256].
//   - tok==0 steps are no-ops (state carries) -> skip uniformly (~1/6 of steps).

#define TT 2048
#define BB 256
#define HIDN 64

__global__ __launch_bounds__(256) void precompute_zx(
    const float* __restrict__ emb,
    const float* __restrict__ W_f, const float* __restrict__ b_f,
    const float* __restrict__ W_b, const float* __restrict__ b_b,
    float* __restrict__ zx) {
  // zx layout: [dir][v][j] = dir*1536 + v*256 + j
  int v   = blockIdx.x % 6;
  int dir = blockIdx.x / 6;
  int j   = threadIdx.x;
  const float* W = dir ? W_b : W_f;
  const float* bv = dir ? b_b : b_f;
  float acc = bv[j];
#pragma unroll
  for (int e = 0; e < 64; ++e)
    acc = fmaf(emb[v * 64 + e], W[e * 256 + j], acc);
  zx[dir * 1536 + v * 256 + j] = acc;
}

__device__ __forceinline__ float sigm(float x) {
  return 1.0f / (1.0f + expf(-x));
}

__global__ __launch_bounds__(256) void lstm_main(
    const int* __restrict__ tokens,
    const float* __restrict__ U_f,
    const float* __restrict__ zx,
    const float* __restrict__ W_d,
    const float* __restrict__ b_d,
    float* __restrict__ out) {
  const int b   = blockIdx.x;
  const int tid = threadIdx.x;

  __shared__ int   tok_s[TT];          // 8 KB
  __shared__ float zx_s[6 * 256];      // 6 KB (fwd table)
  __shared__ float h_s[HIDN] __attribute__((aligned(16)));
  __shared__ float act_s[256];

  // stage tokens (coalesced) and fwd zx table
  for (int i = tid; i < TT; i += 256) tok_s[i] = tokens[b * TT + i];
  for (int i = tid; i < 1536; i += 256) zx_s[i] = zx[i];
  if (tid < HIDN) h_s[tid] = 0.0f;

  // U column j in registers: Ucol[k] = U_f[k][j]
  float Ucol[64];
#pragma unroll
  for (int k = 0; k < 64; ++k) Ucol[k] = U_f[k * 256 + tid];

  __syncthreads();

  float h_reg = 0.0f, c_reg = 0.0f;   // live in wave 0 (tid<64)
  const int wave = tid >> 6;          // 0:i 1:f 2:g 3:o — wave-uniform

  for (int t = 0; t < TT; ++t) {
    const int tok = tok_s[t];
    if (tok != 0) {                   // uniform branch: masked steps are no-ops
      // z[tid] = zx[tok][tid] + sum_k h[k]*U[k][tid]
      float a0 = 0.f, a1 = 0.f, a2 = 0.f, a3 = 0.f;
#pragma unroll
      for (int k = 0; k < 64; k += 4) {
        const float4 hv = *(const float4*)&h_s[k];
        a0 = fmaf(hv.x, Ucol[k + 0], a0);
        a1 = fmaf(hv.y, Ucol[k + 1], a1);
        a2 = fmaf(hv.z, Ucol[k + 2], a2);
        a3 = fmaf(hv.w, Ucol[k + 3], a3);
      }
      const float z = zx_s[tok * 256 + tid] + ((a0 + a1) + (a2 + a3));
      // activation: tanh for gate g (wave 2), sigmoid otherwise
      act_s[tid] = (wave == 2) ? tanhf(z) : sigm(z);
      __syncthreads();
      if (tid < HIDN) {
        const float ai = act_s[tid];
        const float af = act_s[tid + 64];
        const float ag = act_s[tid + 128];
        const float ao = act_s[tid + 192];
        c_reg = fmaf(af, c_reg, ai * ag);
        h_reg = ao * tanhf(c_reg);
        h_s[tid] = h_reg;
      }
      __syncthreads();
    }
  }

  // backward direction: single step from zero state at t = T-1, then dense.
  if (tid < HIDN) {
    const int tokL = tok_s[TT - 1];
    float hb = 0.0f;
    if (tokL != 0) {
      const float zi = zx[1536 + tokL * 256 + tid];
      const float zg = zx[1536 + tokL * 256 + tid + 128];
      const float zo = zx[1536 + tokL * 256 + tid + 192];
      const float cn = sigm(zi) * tanhf(zg);   // c0 = 0 -> forget term vanishes
      hb = sigm(zo) * tanhf(cn);
    }
    float p = fmaf(h_reg, W_d[tid], hb * W_d[64 + tid]);
#pragma unroll
    for (int off = 32; off > 0; off >>= 1)
      p += __shfl_xor(p, off, 64);
    if (tid == 0) out[b] = p + b_d[0];
  }
}

extern "C" void kernel_launch(void* const* d_in, const int* in_sizes, int n_in,
                              void* d_out, int out_size, void* d_ws, size_t ws_size,
                              hipStream_t stream) {
  const int*   tokens = (const int*)d_in[0];
  const float* emb    = (const float*)d_in[1];
  const float* W_f    = (const float*)d_in[2];
  const float* U_f    = (const float*)d_in[3];
  const float* b_f    = (const float*)d_in[4];
  const float* W_b    = (const float*)d_in[5];
  const float* U_b    = (const float*)d_in[6];
  (void)U_b; // bwd direction is a single step from zero state: h@U_b == 0
  const float* b_b    = (const float*)d_in[7];
  const float* W_d    = (const float*)d_in[8];
  const float* b_d    = (const float*)d_in[9];
  float* out = (float*)d_out;
  float* zx  = (float*)d_ws;  // [2][6][256] floats = 12 KB

  precompute_zx<<<12, 256, 0, stream>>>(emb, W_f, b_f, W_b, b_b, zx);
  lstm_main<<<BB, 256, 0, stream>>>(tokens, U_f, zx, W_d, b_d, out);
}

// Round 2
// 938.125 us; speedup vs baseline: 1.2611x; 1.2611x over previous
//
#include <hip/hip_runtime.h>

// Bidirectional masked LSTM, only last timestep consumed.
//   B=256, T=2048, VOCAB=6, EMB=64, HID=64.
// Algebraic reductions (validated round 0, absmax 0.0):
//   - bwd direction at t=T-1 == ONE lstm step from zero state (U_b unused).
//   - x@W+b has only 6 values per direction -> zx tables [6][256].
//   - tok==0 steps are complete no-ops -> uniform skip (~1/6 of steps).
// This round: latency-focused restructure.
//   - wave w owns units [16w,16w+16) x 4 gates; gate gather via 3 intra-wave
//     shuffles; c/h update in-place -> ONE barrier/step (double-buffered h).
//   - fast sigmoid/tanh via v_exp_f32 + v_rcp_f32, branch-free.
//   - tok register prefetch; zx table computed in-kernel (no precursor launch).

#define TT 2048
#define HIDN 64
#define L2E 1.4426950408889634f

__device__ __forceinline__ float fexp2(float x) { return __builtin_amdgcn_exp2f(x); }
__device__ __forceinline__ float frcp(float x)  { return __builtin_amdgcn_rcpf(x); }
// sigma(x) = 1/(1+2^(-x*L2E)); tanh(x) = 2*sigma(2x)-1
__device__ __forceinline__ float fsigm(float x) { return frcp(1.f + fexp2(-L2E * x)); }
__device__ __forceinline__ float ftanh(float x) { return fmaf(2.f, frcp(1.f + fexp2(-2.f * L2E * x)), -1.f); }

__global__ __launch_bounds__(256) void lstm_fused(
    const int* __restrict__ tokens,
    const float* __restrict__ emb,
    const float* __restrict__ W_f, const float* __restrict__ U_f, const float* __restrict__ b_f,
    const float* __restrict__ W_b, const float* __restrict__ b_b,
    const float* __restrict__ W_d, const float* __restrict__ b_d,
    float* __restrict__ out)
{
  const int b    = blockIdx.x;
  const int tid  = threadIdx.x;
  const int lane = tid & 63;
  const int wv   = tid >> 6;      // wave 0..3
  const int ug   = lane & 15;     // unit within wave's group
  const int g    = lane >> 4;     // gate 0:i 1:f 2:g(tanh) 3:o
  const int u    = wv * 16 + ug;  // hidden unit 0..63
  const int col  = g * 64 + u;    // column in z / U / zx

  __shared__ int   tok_s[TT + 8];
  __shared__ float emb_s[6 * 64];
  __shared__ float zx_s [6 * 256];   // fwd table
  __shared__ float zxb_s[6 * 256];   // bwd table (epilogue only)
  __shared__ float hbuf[2][HIDN] __attribute__((aligned(16)));

  // ---- stage tokens (int4 coalesced) + emb; zero h buffers ----
  {
    const int4* tsrc = (const int4*)(tokens + b * TT);
    int4* tdst = (int4*)tok_s;
    for (int i = tid; i < TT / 4; i += 256) tdst[i] = tsrc[i];
    if (tid < 8) tok_s[TT + tid] = 0;
    for (int i = tid; i < 384; i += 256) emb_s[i] = emb[i];
    if (tid < HIDN) { hbuf[0][tid] = 0.f; hbuf[1][tid] = 0.f; }
  }
  __syncthreads();

  // ---- in-kernel zx tables: thread owns column j=tid, both dirs.
  //      W is read once per block (coalesced); emb broadcast from LDS. ----
  {
    float af[6], ab[6];
#pragma unroll
    for (int v = 0; v < 6; ++v) { af[v] = b_f[tid]; ab[v] = b_b[tid]; }
    for (int e = 0; e < 64; ++e) {
      const float wf = W_f[e * 256 + tid];
      const float wb = W_b[e * 256 + tid];
#pragma unroll
      for (int v = 0; v < 6; ++v) {
        af[v] = fmaf(emb_s[v * 64 + e], wf, af[v]);
        ab[v] = fmaf(emb_s[v * 64 + e], wb, ab[v]);
      }
    }
#pragma unroll
    for (int v = 0; v < 6; ++v) {
      zx_s [v * 256 + tid] = af[v];
      zxb_s[v * 256 + tid] = ab[v];
    }
  }

  // ---- U column in registers (independent of zx compute, overlaps) ----
  float Ucol[64];
#pragma unroll
  for (int k = 0; k < 64; ++k) Ucol[k] = U_f[k * 256 + col];

  __syncthreads();

  // branch-free activation constants: y = ya*rcp(1+exp2(z*m1)) + yb
  const float m1 = (g == 2) ? (-2.f * L2E) : (-L2E);
  const float ya = (g == 2) ? 2.f : 1.f;
  const float yb = (g == 2) ? -1.f : 0.f;

  float c_reg = 0.f;                 // valid on g==0 lanes
  int   p     = 0;                   // current h buffer
  int   tok   = tok_s[0];

  for (int t = 0; t < TT; ++t) {
    const int tok_n = tok_s[t + 1];  // prefetch (padded with 0)
    if (tok != 0) {                  // block-uniform branch
      const float zxv = zx_s[tok * 256 + col];   // hides under FMA chain
      float a0 = 0.f, a1 = 0.f, a2 = 0.f, a3 = 0.f;
      const float4* hb4 = (const float4*)&hbuf[p][0];
#pragma unroll
      for (int k4 = 0; k4 < 16; ++k4) {
        const float4 hv = hb4[k4];
        a0 = fmaf(hv.x, Ucol[4 * k4 + 0], a0);
        a1 = fmaf(hv.y, Ucol[4 * k4 + 1], a1);
        a2 = fmaf(hv.z, Ucol[4 * k4 + 2], a2);
        a3 = fmaf(hv.w, Ucol[4 * k4 + 3], a3);
      }
      const float z = zxv + ((a0 + a1) + (a2 + a3));
      const float y = fmaf(ya, frcp(1.f + fexp2(z * m1)), yb);
      // gather f,g,o gate values to the g==0 lanes of this wave
      const float vf = __shfl(y, ug + 16, 64);
      const float vg = __shfl(y, ug + 32, 64);
      const float vo = __shfl(y, ug + 48, 64);
      c_reg = fmaf(vf, c_reg, y * vg);     // y == i-act on g0 lanes
      const float hn = vo * ftanh(c_reg);
      if (g == 0) hbuf[p ^ 1][u] = hn;
      __syncthreads();                      // covers RAW and WAR (double buffer)
      p ^= 1;
    }
    tok = tok_n;
  }

  // ---- epilogue: bwd single step from zero state + dense + reduce ----
  if (tid < HIDN) {
    const float hf   = hbuf[p][tid];
    const int   tokL = tok_s[TT - 1];
    float hbv = 0.f;
    if (tokL != 0) {
      const float zi = zxb_s[tokL * 256 + tid];
      const float zg = zxb_s[tokL * 256 + 128 + tid];
      const float zo = zxb_s[tokL * 256 + 192 + tid];
      const float cn = fsigm(zi) * ftanh(zg);   // c0=0 -> forget term vanishes
      hbv = fsigm(zo) * ftanh(cn);
    }
    float pr = fmaf(hf, W_d[tid], hbv * W_d[64 + tid]);
#pragma unroll
    for (int off = 32; off > 0; off >>= 1) pr += __shfl_xor(pr, off, 64);
    if (tid == 0) out[b] = pr + b_d[0];
  }
}

extern "C" void kernel_launch(void* const* d_in, const int* in_sizes, int n_in,
                              void* d_out, int out_size, void* d_ws, size_t ws_size,
                              hipStream_t stream) {
  const int*   tokens = (const int*)d_in[0];
  const float* emb    = (const float*)d_in[1];
  const float* W_f    = (const float*)d_in[2];
  const float* U_f    = (const float*)d_in[3];
  const float* b_f    = (const float*)d_in[4];
  const float* W_b    = (const float*)d_in[5];
  const float* U_b    = (const float*)d_in[6];
  (void)U_b;  // bwd is a single step from zero state: h@U_b == 0
  const float* b_b    = (const float*)d_in[7];
  const float* W_d    = (const float*)d_in[8];
  const float* b_d    = (const float*)d_in[9];
  float* out = (float*)d_out;
  (void)d_ws; (void)ws_size;

  lstm_fused<<<256, 256, 0, stream>>>(tokens, emb, W_f, U_f, b_f, W_b, b_b,
                                      W_d, b_d, out);
}

// Round 3
// 807.780 us; speedup vs baseline: 1.4646x; 1.1614x over previous
//
#include <hip/hip_runtime.h>

// Bidirectional masked LSTM, only last timestep consumed.
//   B=256, T=2048, VOCAB=6, EMB=64, HID=64.  One block per batch element.
// Algebraic reductions (validated rounds 0-1, absmax 0.0):
//   - bwd direction at t=T-1 == ONE lstm step from zero state (U_b unused).
//   - x@W+b has only 6 values per direction -> zx tables.
//   - tok==0 steps are complete no-ops -> uniform skip (~1/6 of steps).
// Round-2 restructure (LDS pipe was the bottleneck: 64x ds_read_b128/CU/step):
//   - k-slice decomposition: wave wv owns units AND k-slice [16wv,16wv+16).
//     h values it needs are the ones it computed -> broadcast via v_readlane
//     to SGPRs (VALU pipe), FMA with scalar operand.
//   - cross-wave z reduction via tiny partial buffer: 1 ds_write_b128 +
//     4 ds_read_b32 per thread per step (padded layout, 2-way = free).
//   - ONE barrier/step, double-buffered partials, h never in LDS in-loop.

#define TT 2048
#define L2E 1.4426950408889634f

__device__ __forceinline__ float fexp2(float x) { return __builtin_amdgcn_exp2f(x); }
__device__ __forceinline__ float frcp(float x)  { return __builtin_amdgcn_rcpf(x); }
__device__ __forceinline__ float fsigm(float x) { return frcp(1.f + fexp2(-L2E * x)); }
__device__ __forceinline__ float ftanh(float x) { return fmaf(2.f, frcp(1.f + fexp2(-2.f * L2E * x)), -1.f); }
__device__ __forceinline__ float readlane_f(float v, int l) {
  return __builtin_bit_cast(float, __builtin_amdgcn_readlane(__builtin_bit_cast(int, v), l));
}

__global__ __launch_bounds__(256) void lstm_fused(
    const int* __restrict__ tokens,
    const float* __restrict__ emb,
    const float* __restrict__ W_f, const float* __restrict__ U_f, const float* __restrict__ b_f,
    const float* __restrict__ W_b, const float* __restrict__ b_b,
    const float* __restrict__ W_d, const float* __restrict__ b_d,
    float* __restrict__ out)
{
  const int b    = blockIdx.x;
  const int tid  = threadIdx.x;
  const int lane = tid & 63;
  const int wv   = tid >> 6;      // wave 0..3: owns units & k-slice [16wv,16wv+16)
  const int g    = lane >> 4;     // gate 0:i 1:f 2:g(tanh) 3:o
  const int ug   = lane & 15;

  __shared__ int   tok_s[TT + 8];
  __shared__ float emb_s[6 * 64];
  __shared__ float zx_s [6 * 288];            // fwd, padded: [v][g*72+u]
  __shared__ float zxb_s[6 * 256];            // bwd (epilogue only)
  __shared__ float part[2][4][288] __attribute__((aligned(16)));  // [buf][wv][g*72+c]
  __shared__ float h_s[64];

  // ---- stage tokens (int4) + emb ----
  {
    const int4* tsrc = (const int4*)(tokens + b * TT);
    int4* tdst = (int4*)tok_s;
    for (int i = tid; i < TT / 4; i += 256) tdst[i] = tsrc[i];
    if (tid < 8) tok_s[TT + tid] = 0;
    for (int i = tid; i < 384; i += 256) emb_s[i] = emb[i];
  }
  __syncthreads();

  // ---- zx tables (thread owns column tid, both dirs) ----
  {
    float af[6], ab[6];
#pragma unroll
    for (int v = 0; v < 6; ++v) { af[v] = b_f[tid]; ab[v] = b_b[tid]; }
    for (int e = 0; e < 64; ++e) {
      const float wf = W_f[e * 256 + tid];
      const float wb = W_b[e * 256 + tid];
#pragma unroll
      for (int v = 0; v < 6; ++v) {
        af[v] = fmaf(emb_s[v * 64 + e], wf, af[v]);
        ab[v] = fmaf(emb_s[v * 64 + e], wb, ab[v]);
      }
    }
#pragma unroll
    for (int v = 0; v < 6; ++v) {
      zx_s [v * 288 + (tid >> 6) * 72 + (tid & 63)] = af[v];
      zxb_s[v * 256 + tid] = ab[v];
    }
  }

  // ---- U fragment: this lane's 4 columns x its wave's 16 k's ----
  // partial-compute columns: c_j = 64*g + 4*ug + j, j=0..3
  float4 Uc[16];
#pragma unroll
  for (int r = 0; r < 16; ++r)
    Uc[r] = *(const float4*)&U_f[(16 * wv + r) * 256 + 64 * g + 4 * ug];

  __syncthreads();

  // reduce-side column for this lane: (gate g, unit 16wv+ug)
  const int roff = g * 72 + 16 * wv + ug;
  // branch-free activation constants: y = ya*rcp(1+exp2(z*m1)) + yb
  const float m1 = (g == 2) ? (-2.f * L2E) : (-L2E);
  const float ya = (g == 2) ? 2.f : 1.f;
  const float yb = (g == 2) ? -1.f : 0.f;

  float h_reg = 0.f;   // lanes 0-15 of wave wv: h[16wv+ug] (others: garbage ok)
  float c_reg = 0.f;
  int   buf   = 0;
  int   tok   = __builtin_amdgcn_readfirstlane(tok_s[0]);

  for (int t = 0; t < TT; ++t) {
    const int tok_n = __builtin_amdgcn_readfirstlane(tok_s[t + 1]);
    if (tok != 0) {                       // provably uniform branch
      // partials over this wave's k-slice; h via readlane -> scalar-operand FMA
      float p0 = 0.f, p1 = 0.f, p2 = 0.f, p3 = 0.f;
#pragma unroll
      for (int r = 0; r < 16; ++r) {
        const float hk = readlane_f(h_reg, r);
        p0 = fmaf(hk, Uc[r].x, p0);
        p1 = fmaf(hk, Uc[r].y, p1);
        p2 = fmaf(hk, Uc[r].z, p2);
        p3 = fmaf(hk, Uc[r].w, p3);
      }
      *(float4*)&part[buf][wv][g * 72 + 4 * ug] = float4{p0, p1, p2, p3};
      const float zxv = zx_s[tok * 288 + roff];   // independent, pre-barrier
      __syncthreads();
      const float z = ((part[buf][0][roff] + part[buf][1][roff]) +
                       (part[buf][2][roff] + part[buf][3][roff])) + zxv;
      const float y = fmaf(ya, frcp(1.f + fexp2(z * m1)), yb);
      // gather f,g,o gates for unit 16wv+ug (valid on g==0 lanes)
      const float vf = __shfl(y, ug + 16, 64);
      const float vg = __shfl(y, ug + 32, 64);
      const float vo = __shfl(y, ug + 48, 64);
      c_reg = fmaf(vf, c_reg, y * vg);    // y == i-act on g==0 lanes
      h_reg = vo * ftanh(c_reg);
      buf ^= 1;                           // WAR safe: 2 barriers between reuse
    }
    tok = tok_n;
  }

  // ---- epilogue: publish h, bwd single step, dense + reduce ----
  if (lane < 16) h_s[16 * wv + ug] = h_reg;
  __syncthreads();
  if (tid < 64) {
    const float hf   = h_s[tid];
    const int   tokL = tok_s[TT - 1];
    float hbv = 0.f;
    if (tokL != 0) {
      const float zi = zxb_s[tokL * 256 + tid];
      const float zg = zxb_s[tokL * 256 + 128 + tid];
      const float zo = zxb_s[tokL * 256 + 192 + tid];
      const float cn = fsigm(zi) * ftanh(zg);   // c0=0 -> forget term vanishes
      hbv = fsigm(zo) * ftanh(cn);
    }
    float pr = fmaf(hf, W_d[tid], hbv * W_d[64 + tid]);
#pragma unroll
    for (int off = 32; off > 0; off >>= 1) pr += __shfl_xor(pr, off, 64);
    if (tid == 0) out[b] = pr + b_d[0];
  }
}

extern "C" void kernel_launch(void* const* d_in, const int* in_sizes, int n_in,
                              void* d_out, int out_size, void* d_ws, size_t ws_size,
                              hipStream_t stream) {
  const int*   tokens = (const int*)d_in[0];
  const float* emb    = (const float*)d_in[1];
  const float* W_f    = (const float*)d_in[2];
  const float* U_f    = (const float*)d_in[3];
  const float* b_f    = (const float*)d_in[4];
  const float* W_b    = (const float*)d_in[5];
  const float* U_b    = (const float*)d_in[6];
  (void)U_b;  // bwd is a single step from zero state: h@U_b == 0
  const float* b_b    = (const float*)d_in[7];
  const float* W_d    = (const float*)d_in[8];
  const float* b_d    = (const float*)d_in[9];
  float* out = (float*)d_out;
  (void)d_ws; (void)ws_size;

  lstm_fused<<<256, 256, 0, stream>>>(tokens, emb, W_f, U_f, b_f, W_b, b_b,
                                      W_d, b_d, out);
}

// Round 4
// 740.662 us; speedup vs baseline: 1.5973x; 1.0906x over previous
//
#include <hip/hip_runtime.h>

// Bidirectional masked LSTM, only last timestep consumed.
//   B=256, T=2048, VOCAB=6, EMB=64, HID=64.  One block per batch element/CU.
// Algebraic reductions (validated rounds 0-2, absmax 0.0):
//   - bwd direction at t=T-1 == ONE lstm step from zero state (U_b unused).
//   - x@W+b has only 6 values per direction -> zx tables.
//   - tok==0 steps are complete no-ops -> token stream COMPACTED once,
//     main loop runs only active steps (no branch at all).
// Round-3 fixes (rocprof: FETCH_SIZE=1.8GB, VGPR=48 -> U was re-fetched from
// L2 every step at ~36TB/s = L2 BW ceiling; b128 partial-write = 8-way conflict):
//   - __launch_bounds__(256,1) + asm reg-pin: U column LIVES in VGPRs.
//   - gate-split: wave g owns gate g for all 64 units; h,c REPLICATED per-lane
//     in every wave; h broadcast via v_readlane (VALU pipe, zero LDS).
//   - per step cross-wave traffic: 1 ds_write_b32 + 4 ds_read_b32 (all 2-way
//     bank aliasing = free), ONE barrier, double-buffered act exchange.

#define TT 2048
#define L2E 1.4426950408889634f

__device__ __forceinline__ float fexp2(float x) { return __builtin_amdgcn_exp2f(x); }
__device__ __forceinline__ float frcp(float x)  { return __builtin_amdgcn_rcpf(x); }
__device__ __forceinline__ float fsigm(float x) { return frcp(1.f + fexp2(-L2E * x)); }
__device__ __forceinline__ float ftanh(float x) { return fmaf(2.f, frcp(1.f + fexp2(-2.f * L2E * x)), -1.f); }
__device__ __forceinline__ float readlane_f(float v, int l) {
  return __builtin_bit_cast(float, __builtin_amdgcn_readlane(__builtin_bit_cast(int, v), l));
}

__global__ __launch_bounds__(256, 1) void lstm_fused(
    const int* __restrict__ tokens,
    const float* __restrict__ emb,
    const float* __restrict__ W_f, const float* __restrict__ U_f, const float* __restrict__ b_f,
    const float* __restrict__ W_b, const float* __restrict__ b_b,
    const float* __restrict__ W_d, const float* __restrict__ b_d,
    float* __restrict__ out)
{
  const int b    = blockIdx.x;
  const int tid  = threadIdx.x;
  const int lane = tid & 63;      // unit u = lane
  const int g    = tid >> 6;      // wave == gate: 0:i 1:f 2:g(tanh) 3:o

  __shared__ int   tok_s [TT + 8];
  __shared__ int   ctok_s[TT + 8];      // compacted active tokens
  __shared__ float emb_s[6 * 64];
  __shared__ float zx_s [6 * 272];      // fwd table, [v][g*68 + u] (padded)
  __shared__ float zxb_s[6 * 256];      // bwd table (epilogue only)
  __shared__ float act_s[2][4 * 68];    // [buf][g*68 + u]
  __shared__ int   wsum[4];

  // ---- stage tokens (int4) + emb ----
  {
    const int4* tsrc = (const int4*)(tokens + b * TT);
    int4* tdst = (int4*)tok_s;
    for (int i = tid; i < TT / 4; i += 256) tdst[i] = tsrc[i];
    if (tid < 8) { tok_s[TT + tid] = 0; ctok_s[TT + tid] = 0; }
    for (int i = tid; i < 384; i += 256) emb_s[i] = emb[i];
  }
  __syncthreads();

  // ---- compact active tokens: stable parallel scan (8 tokens/thread) ----
  int mytok[8];
  int cnt = 0;
#pragma unroll
  for (int j = 0; j < 8; ++j) {
    mytok[j] = tok_s[tid * 8 + j];
    cnt += (mytok[j] != 0);
  }
  int inc = cnt;                        // wave-inclusive scan
#pragma unroll
  for (int off = 1; off < 64; off <<= 1) {
    int v = __shfl_up(inc, off, 64);
    if (lane >= off) inc += v;
  }
  if (lane == 63) wsum[g] = inc;
  __syncthreads();
  int base = 0;
#pragma unroll
  for (int w = 0; w < 4; ++w) base += (w < g) ? wsum[w] : 0;
  int pos = base + inc - cnt;           // exclusive global offset
#pragma unroll
  for (int j = 0; j < 8; ++j)
    if (mytok[j] != 0) ctok_s[pos++] = mytok[j];
  const int nact = __builtin_amdgcn_readfirstlane(wsum[0] + wsum[1] + wsum[2] + wsum[3]);

  // ---- zx tables (thread owns column (g,lane), both dirs) ----
  {
    float af[6], ab[6];
#pragma unroll
    for (int v = 0; v < 6; ++v) { af[v] = b_f[tid]; ab[v] = b_b[tid]; }
    for (int e = 0; e < 64; ++e) {
      const float wf = W_f[e * 256 + tid];
      const float wb = W_b[e * 256 + tid];
#pragma unroll
      for (int v = 0; v < 6; ++v) {
        af[v] = fmaf(emb_s[v * 64 + e], wf, af[v]);
        ab[v] = fmaf(emb_s[v * 64 + e], wb, ab[v]);
      }
    }
#pragma unroll
    for (int v = 0; v < 6; ++v) {
      zx_s [v * 272 + g * 68 + lane] = af[v];
      zxb_s[v * 256 + tid] = ab[v];
    }
  }

  // ---- U column for (gate g, unit lane) PINNED in VGPRs ----
  float Ucol[64];
#pragma unroll
  for (int k = 0; k < 64; ++k) {
    Ucol[k] = U_f[k * 256 + (g << 6) + lane];
    asm volatile("" : "+v"(Ucol[k]));   // forbid sinking/remat of the load
  }

  __syncthreads();

  // wave-uniform activation constants: y = ya*rcp(1+exp2(z*m1)) + yb
  const float m1 = (g == 2) ? (-2.f * L2E) : (-L2E);
  const float ya = (g == 2) ? 2.f : 1.f;
  const float yb = (g == 2) ? -1.f : 0.f;
  const int   goff = g * 68 + lane;

  // h,c replicated per-lane in EVERY wave: lane l holds h[l], c[l]
  float h_reg = 0.f, c_reg = 0.f;
  int   buf = 0;
  int   tokc = ctok_s[0];

  for (int s = 0; s < nact; ++s) {
    const int tokn = ctok_s[s + 1];              // prefetch (pad-safe)
    const float zxv = zx_s[tokc * 272 + goff];   // issues under FMA block
    float a0 = 0.f, a1 = 0.f, a2 = 0.f, a3 = 0.f;
#pragma unroll
    for (int k = 0; k < 64; k += 4) {
      a0 = fmaf(readlane_f(h_reg, k + 0), Ucol[k + 0], a0);
      a1 = fmaf(readlane_f(h_reg, k + 1), Ucol[k + 1], a1);
      a2 = fmaf(readlane_f(h_reg, k + 2), Ucol[k + 2], a2);
      a3 = fmaf(readlane_f(h_reg, k + 3), Ucol[k + 3], a3);
    }
    const float z = zxv + ((a0 + a1) + (a2 + a3));
    const float y = fmaf(ya, frcp(1.f + fexp2(z * m1)), yb);
    act_s[buf][goff] = y;
    __syncthreads();
    const float ai  = act_s[buf][lane];
    const float af2 = act_s[buf][68 + lane];
    const float ag  = act_s[buf][136 + lane];
    const float ao  = act_s[buf][204 + lane];
    c_reg = fmaf(af2, c_reg, ai * ag);           // replicated update, all waves
    h_reg = ao * ftanh(c_reg);
    buf ^= 1;                                    // WAR-safe: 2 barriers apart
    tokc = tokn;
  }

  // ---- epilogue: bwd single step from zero state + dense + reduce ----
  if (tid < 64) {                                // wave 0 holds h[lane] = h_reg
    const float hf   = h_reg;
    const int   tokL = tok_s[TT - 1];
    float hbv = 0.f;
    if (tokL != 0) {
      const float zi = zxb_s[tokL * 256 + tid];
      const float zg = zxb_s[tokL * 256 + 128 + tid];
      const float zo = zxb_s[tokL * 256 + 192 + tid];
      const float cn = fsigm(zi) * ftanh(zg);    // c0=0 -> forget term vanishes
      hbv = fsigm(zo) * ftanh(cn);
    }
    float pr = fmaf(hf, W_d[tid], hbv * W_d[64 + tid]);
#pragma unroll
    for (int off = 32; off > 0; off >>= 1) pr += __shfl_xor(pr, off, 64);
    if (tid == 0) out[b] = pr + b_d[0];
  }
}

extern "C" void kernel_launch(void* const* d_in, const int* in_sizes, int n_in,
                              void* d_out, int out_size, void* d_ws, size_t ws_size,
                              hipStream_t stream) {
  const int*   tokens = (const int*)d_in[0];
  const float* emb    = (const float*)d_in[1];
  const float* W_f    = (const float*)d_in[2];
  const float* U_f    = (const float*)d_in[3];
  const float* b_f    = (const float*)d_in[4];
  const float* W_b    = (const float*)d_in[5];
  const float* U_b    = (const float*)d_in[6];
  (void)U_b;  // bwd is a single step from zero state: h@U_b == 0
  const float* b_b    = (const float*)d_in[7];
  const float* W_d    = (const float*)d_in[8];
  const float* b_d    = (const float*)d_in[9];
  float* out = (float*)d_out;
  (void)d_ws; (void)ws_size;

  lstm_fused<<<256, 256, 0, stream>>>(tokens, emb, W_f, U_f, b_f, W_b, b_b,
                                      W_d, b_d, out);
}

// Round 7
// 740.449 us; speedup vs baseline: 1.5978x; 1.0003x over previous
//
#include <hip/hip_runtime.h>

// Bidirectional masked LSTM, only last timestep consumed.
//   B=256, T=2048, VOCAB=6, EMB=64, HID=64.  One block per batch element/CU.
// Algebraic reductions (validated rounds 0-3, absmax 0.0):
//   - bwd direction at t=T-1 == ONE lstm step from zero state (U_b unused).
//   - x@W+b has only 6 values per direction -> zx tables.
//   - tok==0 steps are no-ops -> token stream compacted once; loop runs only
//     active steps.
// Rounds 4-6 single hypothesis (rocprof R3: FETCH_SIZE 1854MB @ VGPR=52 ->
// compiler re-loads U every step; ~28TB of L1/L2 traffic = the real limiter):
//   force U register-resident by (a) VOLATILE loads (no remat), (b) 64 NAMED
//   scalar locals (no array->scratch demotion), (c) per-iteration asm pins.
//   Core predicted delta: FETCH_SIZE 1854MB -> ~30MB, VGPR 52 -> ~120-160,
//   dur 703 -> ~350-430us.  (R5/R6 benches lost to GPU acquisition timeout.)

#define TT 2048
#define L2E 1.4426950408889634f

__device__ __forceinline__ float fexp2(float x) { return __builtin_amdgcn_exp2f(x); }
__device__ __forceinline__ float frcp(float x)  { return __builtin_amdgcn_rcpf(x); }
__device__ __forceinline__ float fsigm(float x) { return frcp(1.f + fexp2(-L2E * x)); }
__device__ __forceinline__ float ftanh(float x) { return fmaf(2.f, frcp(1.f + fexp2(-2.f * L2E * x)), -1.f); }
__device__ __forceinline__ float readlane_f(float v, int l) {
  return __builtin_bit_cast(float, __builtin_amdgcn_readlane(__builtin_bit_cast(int, v), l));
}

// apply X to 0..63
#define UFOR_ALL(X) \
  X(0)  X(1)  X(2)  X(3)  X(4)  X(5)  X(6)  X(7)  \
  X(8)  X(9)  X(10) X(11) X(12) X(13) X(14) X(15) \
  X(16) X(17) X(18) X(19) X(20) X(21) X(22) X(23) \
  X(24) X(25) X(26) X(27) X(28) X(29) X(30) X(31) \
  X(32) X(33) X(34) X(35) X(36) X(37) X(38) X(39) \
  X(40) X(41) X(42) X(43) X(44) X(45) X(46) X(47) \
  X(48) X(49) X(50) X(51) X(52) X(53) X(54) X(55) \
  X(56) X(57) X(58) X(59) X(60) X(61) X(62) X(63)

#define DECLU(k) float U##k = Uv[(k) * 256 + cb];
#define PINU(k)  asm volatile("" : "+v"(U##k));
#define FMA4(k0, k1, k2, k3)                           \
  a0 = fmaf(readlane_f(h_reg, k0), U##k0, a0);         \
  a1 = fmaf(readlane_f(h_reg, k1), U##k1, a1);         \
  a2 = fmaf(readlane_f(h_reg, k2), U##k2, a2);         \
  a3 = fmaf(readlane_f(h_reg, k3), U##k3, a3);

__global__ __launch_bounds__(256, 1) void lstm_fused(
    const int* __restrict__ tokens,
    const float* __restrict__ emb,
    const float* __restrict__ W_f, const float* __restrict__ U_f, const float* __restrict__ b_f,
    const float* __restrict__ W_b, const float* __restrict__ b_b,
    const float* __restrict__ W_d, const float* __restrict__ b_d,
    float* __restrict__ out)
{
  const int b    = blockIdx.x;
  const int tid  = threadIdx.x;
  const int lane = tid & 63;      // unit u = lane
  const int g    = tid >> 6;      // wave == gate: 0:i 1:f 2:g(tanh) 3:o

  __shared__ int   tok_s [TT + 8];
  __shared__ int   ctok_s[TT + 8];      // compacted active tokens
  __shared__ float emb_s[6 * 64];
  __shared__ float zx_s [6 * 272];      // fwd table, [v][g*68 + u] (padded)
  __shared__ float zxb_s[6 * 256];      // bwd table (epilogue only)
  __shared__ float act_s[2][4 * 68];    // [buf][g*68 + u]
  __shared__ int   wsum[4];

  // ---- stage tokens (int4) + emb ----
  {
    const int4* tsrc = (const int4*)(tokens + b * TT);
    int4* tdst = (int4*)tok_s;
    for (int i = tid; i < TT / 4; i += 256) tdst[i] = tsrc[i];
    if (tid < 8) { tok_s[TT + tid] = 0; ctok_s[TT + tid] = 0; }
    for (int i = tid; i < 384; i += 256) emb_s[i] = emb[i];
  }
  __syncthreads();

  // ---- compact active tokens: stable parallel scan (8 tokens/thread) ----
  int mytok[8];
  int cnt = 0;
#pragma unroll
  for (int j = 0; j < 8; ++j) {
    mytok[j] = tok_s[tid * 8 + j];
    cnt += (mytok[j] != 0);
  }
  int inc = cnt;                        // wave-inclusive scan
#pragma unroll
  for (int off = 1; off < 64; off <<= 1) {
    int v = __shfl_up(inc, off, 64);
    if (lane >= off) inc += v;
  }
  if (lane == 63) wsum[g] = inc;
  __syncthreads();
  int base = 0;
#pragma unroll
  for (int w = 0; w < 4; ++w) base += (w < g) ? wsum[w] : 0;
  int pos = base + inc - cnt;           // exclusive global offset
#pragma unroll
  for (int j = 0; j < 8; ++j)
    if (mytok[j] != 0) ctok_s[pos++] = mytok[j];
  const int nact = __builtin_amdgcn_readfirstlane(wsum[0] + wsum[1] + wsum[2] + wsum[3]);

  // ---- zx tables (thread owns column (g,lane), both dirs) ----
  {
    float af[6], ab[6];
#pragma unroll
    for (int v = 0; v < 6; ++v) { af[v] = b_f[tid]; ab[v] = b_b[tid]; }
    for (int e = 0; e < 64; ++e) {
      const float wf = W_f[e * 256 + tid];
      const float wb = W_b[e * 256 + tid];
#pragma unroll
      for (int v = 0; v < 6; ++v) {
        af[v] = fmaf(emb_s[v * 64 + e], wf, af[v]);
        ab[v] = fmaf(emb_s[v * 64 + e], wb, ab[v]);
      }
    }
#pragma unroll
    for (int v = 0; v < 6; ++v) {
      zx_s [v * 272 + g * 68 + lane] = af[v];
      zxb_s[v * 256 + tid] = ab[v];
    }
  }

  // ---- U column for (gate g, unit lane): 64 NAMED scalars, VOLATILE loads.
  //      Volatile -> exactly one load each (no remat); named scalars -> no
  //      array->scratch demotion; in-loop pins -> live across backedge. ----
  const volatile float* Uv = U_f;
  const int cb = (g << 6) + lane;
  UFOR_ALL(DECLU)

  __syncthreads();

  // wave-uniform activation constants: y = ya*rcp(1+exp2(z*m1)) + yb
  const float m1 = (g == 2) ? (-2.f * L2E) : (-L2E);
  const float ya = (g == 2) ? 2.f : 1.f;
  const float yb = (g == 2) ? -1.f : 0.f;
  const int   goff = g * 68 + lane;

  // h,c replicated per-lane in EVERY wave: lane l holds h[l], c[l]
  float h_reg = 0.f, c_reg = 0.f;
  int   buf = 0;
  int   tokc = ctok_s[0];

  for (int s = 0; s < nact; ++s) {
    UFOR_ALL(PINU)                               // zero-instruction liveness pin

    const int tokn = ctok_s[s + 1];              // prefetch (pad-safe)
    const float zxv = zx_s[tokc * 272 + goff];   // issues under FMA block
    float a0 = 0.f, a1 = 0.f, a2 = 0.f, a3 = 0.f;
    FMA4(0, 1, 2, 3)   FMA4(4, 5, 6, 7)   FMA4(8, 9, 10, 11)  FMA4(12, 13, 14, 15)
    FMA4(16, 17, 18, 19) FMA4(20, 21, 22, 23) FMA4(24, 25, 26, 27) FMA4(28, 29, 30, 31)
    FMA4(32, 33, 34, 35) FMA4(36, 37, 38, 39) FMA4(40, 41, 42, 43) FMA4(44, 45, 46, 47)
    FMA4(48, 49, 50, 51) FMA4(52, 53, 54, 55) FMA4(56, 57, 58, 59) FMA4(60, 61, 62, 63)
    const float z = zxv + ((a0 + a1) + (a2 + a3));
    const float y = fmaf(ya, frcp(1.f + fexp2(z * m1)), yb);
    act_s[buf][goff] = y;
    __syncthreads();
    const float ai  = act_s[buf][lane];
    const float af2 = act_s[buf][68 + lane];
    const float ag  = act_s[buf][136 + lane];
    const float ao  = act_s[buf][204 + lane];
    c_reg = fmaf(af2, c_reg, ai * ag);           // replicated update, all waves
    h_reg = ao * ftanh(c_reg);
    buf ^= 1;                                    // WAR-safe: 2 barriers apart
    tokc = tokn;
  }

  // ---- epilogue: bwd single step from zero state + dense + reduce ----
  if (tid < 64) {                                // wave 0 holds h[lane] = h_reg
    const float hf   = h_reg;
    const int   tokL = tok_s[TT - 1];
    float hbv = 0.f;
    if (tokL != 0) {
      const float zi = zxb_s[tokL * 256 + tid];
      const float zg = zxb_s[tokL * 256 + 128 + tid];
      const float zo = zxb_s[tokL * 256 + 192 + tid];
      const float cn = fsigm(zi) * ftanh(zg);    // c0=0 -> forget term vanishes
      hbv = fsigm(zo) * ftanh(cn);
    }
    float pr = fmaf(hf, W_d[tid], hbv * W_d[64 + tid]);
#pragma unroll
    for (int off = 32; off > 0; off >>= 1) pr += __shfl_xor(pr, off, 64);
    if (tid == 0) out[b] = pr + b_d[0];
  }
}

extern "C" void kernel_launch(void* const* d_in, const int* in_sizes, int n_in,
                              void* d_out, int out_size, void* d_ws, size_t ws_size,
                              hipStream_t stream) {
  const int*   tokens = (const int*)d_in[0];
  const float* emb    = (const float*)d_in[1];
  const float* W_f    = (const float*)d_in[2];
  const float* U_f    = (const float*)d_in[3];
  const float* b_f    = (const float*)d_in[4];
  const float* W_b    = (const float*)d_in[5];
  const float* U_b    = (const float*)d_in[6];
  (void)U_b;  // bwd is a single step from zero state: h@U_b == 0
  const float* b_b    = (const float*)d_in[7];
  const float* W_d    = (const float*)d_in[8];
  const float* b_d    = (const float*)d_in[9];
  float* out = (float*)d_out;
  (void)d_ws; (void)ws_size;

  lstm_fused<<<256, 256, 0, stream>>>(tokens, emb, W_f, U_f, b_f, W_b, b_b,
                                      W_d, b_d, out);
}